// Round 1
// baseline (329.348 us; speedup 1.0000x reference)
//
#include <hip/hip_runtime.h>
#include <hip/hip_bf16.h>
#include <stdint.h>

// minGRU: out = (scan(sigmoid gates from x@W_f^T + b_f)) @ W_down^T
// B=4 T=4096 D=1024 E=1536.  Workspace use ~199 MB.

typedef __bf16 bf16x8 __attribute__((ext_vector_type(8)));
typedef float  f32x4  __attribute__((ext_vector_type(4)));

__device__ __forceinline__ uint16_t f32_to_bf16(float f) {
  union { float f; uint32_t u; } v; v.f = f;
  uint32_t r = (v.u + 0x7FFFu + ((v.u >> 16) & 1u)) >> 16;  // RNE
  return (uint16_t)r;
}
__device__ __forceinline__ float bf16_to_f32(uint16_t u) {
  union { uint32_t u; float f; } v; v.u = ((uint32_t)u) << 16;
  return v.f;
}

__device__ __forceinline__ void gload_lds16(const uint16_t* g, uint16_t* l) {
  // async global->LDS, 16B per lane; LDS dest = wave-uniform base + lane*16
  __builtin_amdgcn_global_load_lds(
      (__attribute__((address_space(1))) void*)(g),
      (__attribute__((address_space(3))) void*)(l), 16, 0, 0);
}

// ---------------- cast fp32 -> bf16, x4 vectorized ----------------
__global__ __launch_bounds__(256) void cast_f32_bf16(
    const float* __restrict__ in, uint16_t* __restrict__ out, int n4) {
  int i = blockIdx.x * blockDim.x + threadIdx.x;
  if (i >= n4) return;
  float4 v = reinterpret_cast<const float4*>(in)[i];
  ushort4 o;
  o.x = f32_to_bf16(v.x); o.y = f32_to_bf16(v.y);
  o.z = f32_to_bf16(v.z); o.w = f32_to_bf16(v.w);
  reinterpret_cast<ushort4*>(out)[i] = o;
}

// ---------------- bf16 GEMM, C = A(M,K) * Bt(N,K)^T ----------------
// 128x128 tile, BK=32, 4 waves (2x2), each wave 64x64 via 4x4 16x16x32 MFMA.
// OUT_BF16_BIAS=1: C bf16 with +bias[col];  =0: C fp32, no bias.
template <int OUT_BF16_BIAS>
__global__ __launch_bounds__(256) void gemm_bt(
    const uint16_t* __restrict__ A, const uint16_t* __restrict__ Bt,
    const float* __restrict__ bias, void* __restrict__ Cout,
    int M, int N, int K) {
  __shared__ alignas(16) uint16_t As[128 * 32];
  __shared__ alignas(16) uint16_t Bs[128 * 32];

  const int tid  = threadIdx.x;
  const int wave = tid >> 6;
  const int lane = tid & 63;
  const int m0 = blockIdx.x * 128;
  const int n0 = blockIdx.y * 128;
  const int wr = wave >> 1;   // 2x2 wave grid
  const int wc = wave & 1;

  // staging: each wave stages 32 rows (two 16-row instructions) of A and Bt
  const int srow = lane >> 2;         // 0..15
  const int scol = (lane & 3) << 3;   // 0,8,16,24 bf16 elems
  const uint16_t* Ag = A  + (size_t)(m0 + wave * 32 + srow) * K + scol;
  const uint16_t* Bg = Bt + (size_t)(n0 + wave * 32 + srow) * K + scol;
  uint16_t* AsW0 = &As[(wave * 32) * 32];
  uint16_t* AsW1 = &As[(wave * 32 + 16) * 32];
  uint16_t* BsW0 = &Bs[(wave * 32) * 32];
  uint16_t* BsW1 = &Bs[(wave * 32 + 16) * 32];

  const int lrow = lane & 15;
  const int kgrp = lane >> 4;         // 0..3, 8 bf16 each
  const uint16_t* AsF = &As[(wr * 64 + lrow) * 32 + kgrp * 8];
  const uint16_t* BsF = &Bs[(wc * 64 + lrow) * 32 + kgrp * 8];

  f32x4 acc[4][4] = {};

  for (int kt = 0; kt < K; kt += 32) {
    __syncthreads();                       // prev compute done -> safe to overwrite
    gload_lds16(Ag + kt,                  AsW0);
    gload_lds16(Ag + kt + (size_t)16 * K, AsW1);
    gload_lds16(Bg + kt,                  BsW0);
    gload_lds16(Bg + kt + (size_t)16 * K, BsW1);
    __syncthreads();                       // vmcnt(0) drained by compiler

    bf16x8 af[4], bfr[4];
#pragma unroll
    for (int m = 0; m < 4; ++m)
      af[m] = *reinterpret_cast<const bf16x8*>(AsF + m * 16 * 32);
#pragma unroll
    for (int n = 0; n < 4; ++n)
      bfr[n] = *reinterpret_cast<const bf16x8*>(BsF + n * 16 * 32);
#pragma unroll
    for (int m = 0; m < 4; ++m)
#pragma unroll
      for (int n = 0; n < 4; ++n)
        acc[m][n] = __builtin_amdgcn_mfma_f32_16x16x32_bf16(af[m], bfr[n],
                                                            acc[m][n], 0, 0, 0);
  }

  // C/D layout: col = lane&15, row = (lane>>4)*4 + reg   [verified m89]
  const int r0 = m0 + wr * 64 + (lane >> 4) * 4;
  const int c0 = n0 + wc * 64 + (lane & 15);
  if constexpr (OUT_BF16_BIAS) {
    uint16_t* C = (uint16_t*)Cout;
#pragma unroll
    for (int n = 0; n < 4; ++n) {
      const int col = c0 + n * 16;
      const float bv = bias[col];
#pragma unroll
      for (int m = 0; m < 4; ++m) {
        const int row = r0 + m * 16;
#pragma unroll
        for (int i = 0; i < 4; ++i)
          C[(size_t)(row + i) * N + col] = f32_to_bf16(acc[m][n][i] + bv);
      }
    }
  } else {
    float* C = (float*)Cout;
#pragma unroll
    for (int n = 0; n < 4; ++n) {
      const int col = c0 + n * 16;
#pragma unroll
      for (int m = 0; m < 4; ++m) {
        const int row = r0 + m * 16;
#pragma unroll
        for (int i = 0; i < 4; ++i)
          C[(size_t)(row + i) * N + col] = acc[m][n][i];
      }
    }
  }
}

// ---------------- scan: h_t = a_t*h_{t-1} + v_t,  h_0 = 0.5 ----------------
// a = sigmoid(-kz), v = sigmoid(kz)*g(hx); g(x) = x>=0 ? x+0.5 : sigmoid(x)
__device__ __forceinline__ void gate_val(float kz, float hx, float& a, float& v) {
  float ek = __expf(-fabsf(kz));          // e^{-|k|} in (0,1]
  float r  = 1.0f / (1.0f + ek);          // sigmoid(|k|)
  float z  = (kz >= 0.0f) ? r : ek * r;   // sigmoid(k)
  a        = (kz >= 0.0f) ? ek * r : r;   // sigmoid(-k) = 1-z
  float g;
  if (hx >= 0.0f) {
    g = hx + 0.5f;
  } else {
    float eh = __expf(hx);                // <= 1, safe
    g = eh / (1.0f + eh);
  }
  v = z * g;
}

// pass1: per-chunk affine summary with h_start=0:  (A = prod a, V = local scan end)
__global__ __launch_bounds__(256) void scan_pass1(
    const uint16_t* __restrict__ proj, float* __restrict__ Ac,
    float* __restrict__ Vc, int T, int E, int CH, int L) {
  const int e = blockIdx.x * 256 + threadIdx.x;
  const int c = blockIdx.y;
  const int b = blockIdx.z;
  const int N1 = 2 * E;
  const uint16_t* p = proj + (size_t)(b * T + c * L) * N1 + e;
  float A = 1.0f, V = 0.0f;
  for (int t = 0; t < L; ++t) {
    float kz = bf16_to_f32(p[0]);
    float hx = bf16_to_f32(p[E]);
    float a, v; gate_val(kz, hx, a, v);
    A *= a;
    V = a * V + v;
    p += N1;
  }
  const size_t idx = ((size_t)(b * CH + c)) * E + e;
  Ac[idx] = A; Vc[idx] = V;
}

// pass2: scan chunk summaries -> h at each chunk start
__global__ __launch_bounds__(256) void scan_pass2(
    const float* __restrict__ Ac, const float* __restrict__ Vc,
    float* __restrict__ hstart, int E, int CH) {
  const int e = blockIdx.x * 256 + threadIdx.x;
  const int b = blockIdx.y;
  float h = 0.5f;                          // h_0 = g(0) = 0.5
  for (int c = 0; c < CH; ++c) {
    const size_t idx = ((size_t)(b * CH + c)) * E + e;
    hstart[idx] = h;
    h = Ac[idx] * h + Vc[idx];
  }
}

// pass3: replay chunk with true h_start, emit h (bf16) for GEMM2
__global__ __launch_bounds__(256) void scan_pass3(
    const uint16_t* __restrict__ proj, const float* __restrict__ hstart,
    uint16_t* __restrict__ hout, int T, int E, int CH, int L) {
  const int e = blockIdx.x * 256 + threadIdx.x;
  const int c = blockIdx.y;
  const int b = blockIdx.z;
  const int N1 = 2 * E;
  const uint16_t* p = proj + (size_t)(b * T + c * L) * N1 + e;
  uint16_t* o = hout + (size_t)(b * T + c * L) * E + e;
  float h = hstart[((size_t)(b * CH + c)) * E + e];
  for (int t = 0; t < L; ++t) {
    float kz = bf16_to_f32(p[0]);
    float hx = bf16_to_f32(p[E]);
    float a, v; gate_val(kz, hx, a, v);
    h = a * h + v;
    *o = f32_to_bf16(h);
    p += N1; o += E;
  }
}

extern "C" void kernel_launch(void* const* d_in, const int* in_sizes, int n_in,
                              void* d_out, int out_size, void* d_ws, size_t ws_size,
                              hipStream_t stream) {
  const float* x   = (const float*)d_in[0];
  const float* W_f = (const float*)d_in[1];
  const float* b_f = (const float*)d_in[2];
  const float* W_d = (const float*)d_in[3];
  const int Bb = 4, T = 4096, D = 1024, E = 1536;
  const int M = Bb * T;        // 16384
  const int N1 = 2 * E;        // 3072
  const int CH = 64, L = T / CH;

  char* w = (char*)d_ws;
  uint16_t* x_bf  = (uint16_t*)w; w += (size_t)M * D * 2;     // 32 MB
  uint16_t* Wf_bf = (uint16_t*)w; w += (size_t)N1 * D * 2;    // 6 MB
  uint16_t* Wd_bf = (uint16_t*)w; w += (size_t)D * E * 2;     // 3 MB
  uint16_t* proj  = (uint16_t*)w; w += (size_t)M * N1 * 2;    // 96 MB
  uint16_t* h_bf  = (uint16_t*)w; w += (size_t)M * E * 2;     // 48 MB
  float* Ac     = (float*)w; w += (size_t)Bb * CH * E * 4;    // 1.5 MB
  float* Vc     = (float*)w; w += (size_t)Bb * CH * E * 4;    // 1.5 MB
  float* hstart = (float*)w; w += (size_t)Bb * CH * E * 4;    // 1.5 MB

  cast_f32_bf16<<<M * D / 4 / 256, 256, 0, stream>>>(x, x_bf, M * D / 4);
  cast_f32_bf16<<<N1 * D / 4 / 256, 256, 0, stream>>>(W_f, Wf_bf, N1 * D / 4);
  cast_f32_bf16<<<D * E / 4 / 256, 256, 0, stream>>>(W_d, Wd_bf, D * E / 4);

  // proj = x @ W_f^T + b_f   (bf16 out)
  gemm_bt<1><<<dim3(M / 128, N1 / 128), 256, 0, stream>>>(
      x_bf, Wf_bf, b_f, proj, M, N1, D);

  scan_pass1<<<dim3(E / 256, CH, Bb), 256, 0, stream>>>(proj, Ac, Vc, T, E, CH, L);
  scan_pass2<<<dim3(E / 256, Bb), 256, 0, stream>>>(Ac, Vc, hstart, E, CH);
  scan_pass3<<<dim3(E / 256, CH, Bb), 256, 0, stream>>>(proj, hstart, h_bf, T, E, CH, L);

  // out = h @ W_down^T   (fp32 out, no bias)
  gemm_bt<0><<<dim3(M / 128, D / 128), 256, 0, stream>>>(
      h_bf, Wd_bf, nullptr, d_out, M, D, E);
}

// Round 2
// 296.156 us; speedup vs baseline: 1.1121x; 1.1121x over previous
//
#include <hip/hip_runtime.h>
#include <hip/hip_bf16.h>
#include <stdint.h>

// minGRU: proj = x@W_f^T + b_f (bf16 GEMM) -> chunked linear scan -> out = h@W_down^T
// B=4 T=4096 D=1024 E=1536.
// GEMMs: 256x256 tile, BK=32, 8 waves, 4-deep LDS ring, counted vmcnt(8),
// T2 XOR swizzle (pre-swizzled global src + swizzled ds_read), setprio, XCD swizzle.

typedef __bf16 bf16x8 __attribute__((ext_vector_type(8)));
typedef float  f32x4  __attribute__((ext_vector_type(4)));

__device__ __forceinline__ uint16_t f32_to_bf16(float f) {
  union { float f; uint32_t u; } v; v.f = f;
  uint32_t r = (v.u + 0x7FFFu + ((v.u >> 16) & 1u)) >> 16;  // RNE
  return (uint16_t)r;
}
__device__ __forceinline__ float bf16_to_f32(uint16_t u) {
  union { uint32_t u; float f; } v; v.u = ((uint32_t)u) << 16;
  return v.f;
}

__device__ __forceinline__ void gload_lds16(const uint16_t* g, uint16_t* l) {
  // async global->LDS, 16B/lane; LDS dest = wave-uniform base + lane*16
  __builtin_amdgcn_global_load_lds(
      (__attribute__((address_space(1))) void*)(g),
      (__attribute__((address_space(3))) void*)(l), 16, 0, 0);
}

// ---------------- cast fp32 -> bf16, x4 vectorized ----------------
__global__ __launch_bounds__(256) void cast_f32_bf16(
    const float* __restrict__ in, uint16_t* __restrict__ out, int n4) {
  int i = blockIdx.x * blockDim.x + threadIdx.x;
  if (i >= n4) return;
  float4 v = reinterpret_cast<const float4*>(in)[i];
  ushort4 o;
  o.x = f32_to_bf16(v.x); o.y = f32_to_bf16(v.y);
  o.z = f32_to_bf16(v.z); o.w = f32_to_bf16(v.w);
  reinterpret_cast<ushort4*>(out)[i] = o;
}

// ---------------- bf16 GEMM, C = A(M,K) * Bt(N,K)^T, 256^2 pipelined --------
// grid: 1D, ((M/256)*(N/256)) blocks (must be %8==0 for XCD swizzle), 512 thr.
// LDS ring: 4 bufs x (A 16KB + B 16KB). K-tile t lives in buf[t&3].
// Iter t: fence{vmcnt(8);barrier}; phaseA{ds_read B0-3,A0-3; stage A(t+3);
//   bar; prio1; 16 MFMA; prio0; bar}; phaseB{ds_read A4-7; stage B(t+3);
//   bar; prio1; 16 MFMA; prio0}.
// Staging targets buf[(t+3)&3]==buf[(t-1)&3]: its reads finished before this
// iter's fence barrier -> WAR safe. vmcnt(8)+barrier => tile t landed -> RAW safe.
template <int OUT_BF16_BIAS>
__global__ __launch_bounds__(512, 2) void gemm256(
    const uint16_t* __restrict__ A, const uint16_t* __restrict__ Bt,
    const float* __restrict__ bias, void* __restrict__ Cout,
    int M, int N, int K) {
  __shared__ alignas(16) uint16_t lds[4 * 16384];  // 128 KB

  const int tid  = threadIdx.x;
  const int wave = tid >> 6;
  const int lane = tid & 63;
  const int wr = wave >> 2;      // 0..1  (rows, 128 each)
  const int wc = wave & 3;       // 0..3  (cols, 64 each)

  // XCD-aware bijective swizzle (gridDim.x % 8 == 0)
  const int cpx = gridDim.x >> 3;
  const int swz = ((int)blockIdx.x & 7) * cpx + ((int)blockIdx.x >> 3);
  const int MB  = M >> 8;
  const int m0  = (swz % MB) << 8;
  const int n0  = (swz / MB) << 8;

  const int NT = K >> 5;  // BK = 32

  // ---- staging: linear LDS dest, inverse-swizzled global source ----
  // linear off(j) = (j&1)*8192B + wave*1024B + lane*16B
  //   -> row = (j&1)*128 + wave*16 + (lane>>2), slot kgq = lane&3
  //   global k-group kg = kgq ^ ((row>>1)&3) = (lane&3) ^ ((lane>>3)&3)
  const int srow = wave * 16 + (lane >> 2);
  const int skg  = (lane & 3) ^ ((lane >> 3) & 3);
  const uint16_t* Ag0 = A  + (size_t)(m0 + srow) * K + skg * 8;
  const uint16_t* Ag1 = A  + (size_t)(m0 + 128 + srow) * K + skg * 8;
  const uint16_t* Bg0 = Bt + (size_t)(n0 + srow) * K + skg * 8;
  const uint16_t* Bg1 = Bt + (size_t)(n0 + 128 + srow) * K + skg * 8;
  const int sdw = wave * 512;  // elems

  // ---- swizzled read bases (elems). row*32 + (kg ^ ((row>>1)&3))*8 ----
  const int kgq = (lane >> 4) ^ ((lane >> 1) & 3);
  const int rA = (wr * 128 + (lane & 15)) * 32 + kgq * 8;
  const int rB = (wc * 64  + (lane & 15)) * 32 + kgq * 8;

  f32x4 acc[8][4] = {};

  // prologue: stage tiles 0,1,2 (12 loads)
#pragma unroll
  for (int tt = 0; tt < 3; ++tt) {
    uint16_t* sb = &lds[tt * 16384];
    gload_lds16(Ag0 + tt * 32, sb + sdw);
    gload_lds16(Ag1 + tt * 32, sb + 4096 + sdw);
    gload_lds16(Bg0 + tt * 32, sb + 8192 + sdw);
    gload_lds16(Bg1 + tt * 32, sb + 12288 + sdw);
  }

  for (int t = 0; t < NT; ++t) {
    const uint16_t* Ab = &lds[(t & 3) * 16384 + rA];
    const uint16_t* Bb = &lds[(t & 3) * 16384 + 8192 + rB];
    const int ts = (t + 3 < NT) ? (t + 3) : (NT - 1);  // clamp: uniform vmcnt
    uint16_t* sb = &lds[((t + 3) & 3) * 16384];
    const size_t kofs = (size_t)ts * 32;

    // fence: tile t landed everywhere; never drains below 8 (2 tiles in flight)
    asm volatile("s_waitcnt vmcnt(8)" ::: "memory");
    __builtin_amdgcn_s_barrier();

    // ---- phase A ----
    bf16x8 bfr[4], af[4];
#pragma unroll
    for (int n = 0; n < 4; ++n) bfr[n] = *reinterpret_cast<const bf16x8*>(Bb + n * 512);
#pragma unroll
    for (int m = 0; m < 4; ++m) af[m] = *reinterpret_cast<const bf16x8*>(Ab + m * 512);
    gload_lds16(Ag0 + kofs, sb + sdw);
    gload_lds16(Ag1 + kofs, sb + 4096 + sdw);
    __builtin_amdgcn_s_barrier();
    __builtin_amdgcn_sched_barrier(0);
    __builtin_amdgcn_s_setprio(1);
#pragma unroll
    for (int m = 0; m < 4; ++m)
#pragma unroll
      for (int n = 0; n < 4; ++n)
        acc[m][n] = __builtin_amdgcn_mfma_f32_16x16x32_bf16(af[m], bfr[n],
                                                            acc[m][n], 0, 0, 0);
    __builtin_amdgcn_s_setprio(0);
    __builtin_amdgcn_sched_barrier(0);
    __builtin_amdgcn_s_barrier();

    // ---- phase B ----
#pragma unroll
    for (int m = 0; m < 4; ++m) af[m] = *reinterpret_cast<const bf16x8*>(Ab + (m + 4) * 512);
    gload_lds16(Bg0 + kofs, sb + 8192 + sdw);
    gload_lds16(Bg1 + kofs, sb + 12288 + sdw);
    __builtin_amdgcn_s_barrier();
    __builtin_amdgcn_sched_barrier(0);
    __builtin_amdgcn_s_setprio(1);
#pragma unroll
    for (int m = 0; m < 4; ++m)
#pragma unroll
      for (int n = 0; n < 4; ++n)
        acc[m + 4][n] = __builtin_amdgcn_mfma_f32_16x16x32_bf16(af[m], bfr[n],
                                                                acc[m + 4][n], 0, 0, 0);
    __builtin_amdgcn_s_setprio(0);
    __builtin_amdgcn_sched_barrier(0);
  }
  asm volatile("s_waitcnt vmcnt(0)" ::: "memory");  // drain before LDS dealloc

  // ---- epilogue. C/D layout: col = lane&15, row = (lane>>4)*4 + i ----
  const int r0 = m0 + wr * 128 + (lane >> 4) * 4;
  const int c0 = n0 + wc * 64 + (lane & 15);
  if constexpr (OUT_BF16_BIAS) {
    uint16_t* C = (uint16_t*)Cout;
#pragma unroll
    for (int n = 0; n < 4; ++n) {
      const int col = c0 + n * 16;
      const float bv = bias[col];
#pragma unroll
      for (int m = 0; m < 8; ++m) {
        const int row = r0 + m * 16;
#pragma unroll
        for (int i = 0; i < 4; ++i)
          C[(size_t)(row + i) * N + col] = f32_to_bf16(acc[m][n][i] + bv);
      }
    }
  } else {
    float* C = (float*)Cout;
#pragma unroll
    for (int n = 0; n < 4; ++n) {
      const int col = c0 + n * 16;
#pragma unroll
      for (int m = 0; m < 8; ++m) {
        const int row = r0 + m * 16;
#pragma unroll
        for (int i = 0; i < 4; ++i)
          C[(size_t)(row + i) * N + col] = acc[m][n][i];
      }
    }
  }
}

// ---------------- scan: h_t = a_t*h_{t-1} + v_t,  h_0 = 0.5 ----------------
__device__ __forceinline__ void gate_val(float kz, float hx, float& a, float& v) {
  float ek = __expf(-fabsf(kz));
  float r  = 1.0f / (1.0f + ek);
  float z  = (kz >= 0.0f) ? r : ek * r;   // sigmoid(k)
  a        = (kz >= 0.0f) ? ek * r : r;   // 1 - sigmoid(k)
  float g;
  if (hx >= 0.0f) {
    g = hx + 0.5f;
  } else {
    float eh = __expf(hx);
    g = eh / (1.0f + eh);
  }
  v = z * g;
}

__global__ __launch_bounds__(256) void scan_pass1(
    const uint16_t* __restrict__ proj, float* __restrict__ Ac,
    float* __restrict__ Vc, int T, int E, int CH, int L) {
  const int e = blockIdx.x * 256 + threadIdx.x;
  const int c = blockIdx.y;
  const int b = blockIdx.z;
  const int N1 = 2 * E;
  const uint16_t* p = proj + (size_t)(b * T + c * L) * N1 + e;
  float A = 1.0f, V = 0.0f;
  for (int t = 0; t < L; ++t) {
    float kz = bf16_to_f32(p[0]);
    float hx = bf16_to_f32(p[E]);
    float a, v; gate_val(kz, hx, a, v);
    A *= a;
    V = a * V + v;
    p += N1;
  }
  const size_t idx = ((size_t)(b * CH + c)) * E + e;
  Ac[idx] = A; Vc[idx] = V;
}

__global__ __launch_bounds__(256) void scan_pass2(
    const float* __restrict__ Ac, const float* __restrict__ Vc,
    float* __restrict__ hstart, int E, int CH) {
  const int e = blockIdx.x * 256 + threadIdx.x;
  const int b = blockIdx.y;
  float h = 0.5f;
  for (int c = 0; c < CH; ++c) {
    const size_t idx = ((size_t)(b * CH + c)) * E + e;
    hstart[idx] = h;
    h = Ac[idx] * h + Vc[idx];
  }
}

__global__ __launch_bounds__(256) void scan_pass3(
    const uint16_t* __restrict__ proj, const float* __restrict__ hstart,
    uint16_t* __restrict__ hout, int T, int E, int CH, int L) {
  const int e = blockIdx.x * 256 + threadIdx.x;
  const int c = blockIdx.y;
  const int b = blockIdx.z;
  const int N1 = 2 * E;
  const uint16_t* p = proj + (size_t)(b * T + c * L) * N1 + e;
  uint16_t* o = hout + (size_t)(b * T + c * L) * E + e;
  float h = hstart[((size_t)(b * CH + c)) * E + e];
  for (int t = 0; t < L; ++t) {
    float kz = bf16_to_f32(p[0]);
    float hx = bf16_to_f32(p[E]);
    float a, v; gate_val(kz, hx, a, v);
    h = a * h + v;
    *o = f32_to_bf16(h);
    p += N1; o += E;
  }
}

extern "C" void kernel_launch(void* const* d_in, const int* in_sizes, int n_in,
                              void* d_out, int out_size, void* d_ws, size_t ws_size,
                              hipStream_t stream) {
  const float* x   = (const float*)d_in[0];
  const float* W_f = (const float*)d_in[1];
  const float* b_f = (const float*)d_in[2];
  const float* W_d = (const float*)d_in[3];
  const int Bb = 4, T = 4096, D = 1024, E = 1536;
  const int M = Bb * T;        // 16384
  const int N1 = 2 * E;        // 3072
  const int CH = 64, L = T / CH;

  char* w = (char*)d_ws;
  uint16_t* x_bf  = (uint16_t*)w; w += (size_t)M * D * 2;
  uint16_t* Wf_bf = (uint16_t*)w; w += (size_t)N1 * D * 2;
  uint16_t* Wd_bf = (uint16_t*)w; w += (size_t)D * E * 2;
  uint16_t* proj  = (uint16_t*)w; w += (size_t)M * N1 * 2;
  uint16_t* h_bf  = (uint16_t*)w; w += (size_t)M * E * 2;
  float* Ac     = (float*)w; w += (size_t)Bb * CH * E * 4;
  float* Vc     = (float*)w; w += (size_t)Bb * CH * E * 4;
  float* hstart = (float*)w; w += (size_t)Bb * CH * E * 4;

  cast_f32_bf16<<<M * D / 4 / 256, 256, 0, stream>>>(x, x_bf, M * D / 4);
  cast_f32_bf16<<<N1 * D / 4 / 256, 256, 0, stream>>>(W_f, Wf_bf, N1 * D / 4);
  cast_f32_bf16<<<D * E / 4 / 256, 256, 0, stream>>>(W_d, Wd_bf, D * E / 4);

  // proj = x @ W_f^T + b_f (bf16 out);  grid 64*12=768 (%8==0)
  gemm256<1><<<(M / 256) * (N1 / 256), 512, 0, stream>>>(
      x_bf, Wf_bf, b_f, proj, M, N1, D);

  scan_pass1<<<dim3(E / 256, CH, Bb), 256, 0, stream>>>(proj, Ac, Vc, T, E, CH, L);
  scan_pass2<<<dim3(E / 256, Bb), 256, 0, stream>>>(Ac, Vc, hstart, E, CH);
  scan_pass3<<<dim3(E / 256, CH, Bb), 256, 0, stream>>>(proj, hstart, h_bf, T, E, CH, L);

  // out = h @ W_down^T (fp32 out);  grid 64*4=256 (%8==0)
  gemm256<0><<<(M / 256) * (D / 256), 512, 0, stream>>>(
      h_bf, Wd_bf, nullptr, d_out, M, D, E);
}

// Round 3
// 290.049 us; speedup vs baseline: 1.1355x; 1.0211x over previous
//
#include <hip/hip_runtime.h>
#include <hip/hip_bf16.h>
#include <stdint.h>

// minGRU: proj = x@W_f^T + b_f (bf16 GEMM) -> chunked linear scan -> out = h@W_down^T
// B=4 T=4096 D=1024 E=1536.
// GEMMs: 256x256 tile, BK=32, 8 waves, 4-deep LDS ring, counted vmcnt(8),
// fine 4-phase/K-tile interleave, T2 XOR swizzle, operand-swapped MFMA for
// coalesced epilogue, XCD supertile mapping (requires M==16384).

typedef __bf16 bf16x8 __attribute__((ext_vector_type(8)));
typedef float  f32x4  __attribute__((ext_vector_type(4)));

__device__ __forceinline__ uint16_t f32_to_bf16(float f) {
  union { float f; uint32_t u; } v; v.f = f;
  uint32_t r = (v.u + 0x7FFFu + ((v.u >> 16) & 1u)) >> 16;  // RNE
  return (uint16_t)r;
}
__device__ __forceinline__ float bf16_to_f32(uint16_t u) {
  union { uint32_t u; float f; } v; v.u = ((uint32_t)u) << 16;
  return v.f;
}

__device__ __forceinline__ void gload_lds16(const uint16_t* g, uint16_t* l) {
  __builtin_amdgcn_global_load_lds(
      (__attribute__((address_space(1))) void*)(g),
      (__attribute__((address_space(3))) void*)(l), 16, 0, 0);
}

// ---------------- cast fp32 -> bf16, x4 vectorized ----------------
__global__ __launch_bounds__(256) void cast_f32_bf16(
    const float* __restrict__ in, uint16_t* __restrict__ out, int n4) {
  int i = blockIdx.x * blockDim.x + threadIdx.x;
  if (i >= n4) return;
  float4 v = reinterpret_cast<const float4*>(in)[i];
  ushort4 o;
  o.x = f32_to_bf16(v.x); o.y = f32_to_bf16(v.y);
  o.z = f32_to_bf16(v.z); o.w = f32_to_bf16(v.w);
  reinterpret_cast<ushort4*>(out)[i] = o;
}

// ---------------- bf16 GEMM, C = A(M,K) * Bt(N,K)^T, 256^2 pipelined --------
// LDS ring: 4 bufs x 16KB (A 8KB + B 8KB per... A first 8KB=128rows? layout:
//   buf: A rows 0-255 in [0,16KB): off = (j half)*8KB.. see staging) .
// Per K-tile u (32 K): fence{vmcnt(8);bar}; 4 phases:
//   ph0{rd A0-3,B0-1; stage; bar; 8 MFMA m0-3 x n0-1; bar}
//   ph1{rd A4-7;      stage; bar; 8 MFMA m4-7 x n0-1; bar}
//   ph2{rd B2-3;      stage; bar; 8 MFMA m0-3 x n2-3; bar}
//   ph3{              stage; bar; 8 MFMA m4-7 x n2-3; bar}
// Stage of tile u+3 -> buf[(u+3)&3]=buf[(u-1)&3] (reads done before fence: WAR ok).
// vmcnt(8) keeps tiles u+1,u+2 (8 loads) in flight; tile u landed: RAW ok.
template <int OUT_BF16_BIAS>
__global__ __launch_bounds__(512, 1) void gemm256(
    const uint16_t* __restrict__ A, const uint16_t* __restrict__ Bt,
    const float* __restrict__ bias, void* __restrict__ Cout,
    int M, int N, int K) {
  __shared__ alignas(16) uint16_t lds[4 * 16384];  // 128 KB

  const int tid  = threadIdx.x;
  const int wave = tid >> 6;
  const int lane = tid & 63;
  const int wr = wave >> 2;      // 0..1  (rows, 128 each)
  const int wc = wave & 3;       // 0..3  (cols, 64 each)

  // XCD supertile map: XCD x (= bid&7 under round-robin) owns m-tiles [8x,8x+8)
  const int l  = (int)blockIdx.x >> 3;
  const int x  = (int)blockIdx.x & 7;
  const int m0 = (x * 8 + (l & 7)) << 8;
  const int n0 = (l >> 3) << 8;

  const int NT = K >> 5;  // BK = 32 (NT even: K=1024 or 1536)

  // staging: linear LDS dest, inverse-swizzled global source
  const int srow = wave * 16 + (lane >> 2);
  const int skg  = (lane & 3) ^ ((lane >> 3) & 3);
  const uint16_t* Ag0 = A  + (size_t)(m0 + srow) * K + skg * 8;
  const uint16_t* Ag1 = A  + (size_t)(m0 + 128 + srow) * K + skg * 8;
  const uint16_t* Bg0 = Bt + (size_t)(n0 + srow) * K + skg * 8;
  const uint16_t* Bg1 = Bt + (size_t)(n0 + 128 + srow) * K + skg * 8;
  const int sdw = wave * 512;  // elems

  // swizzled read bases (elems): row*32 + (kg ^ ((row>>1)&3))*8
  const int kgq = (lane >> 4) ^ ((lane >> 1) & 3);
  const int rA = (wr * 128 + (lane & 15)) * 32 + kgq * 8;
  const int rB = (wc * 64  + (lane & 15)) * 32 + kgq * 8;

  f32x4 acc[8][4] = {};

  // prologue: stage tiles 0,1,2
#pragma unroll
  for (int tt = 0; tt < 3; ++tt) {
    uint16_t* sb = &lds[tt * 16384];
    gload_lds16(Ag0 + tt * 32, sb + sdw);
    gload_lds16(Ag1 + tt * 32, sb + 4096 + sdw);
    gload_lds16(Bg0 + tt * 32, sb + 8192 + sdw);
    gload_lds16(Bg1 + tt * 32, sb + 12288 + sdw);
  }

#define PH_BAR_IN()  do { __builtin_amdgcn_s_barrier(); \
                          __builtin_amdgcn_sched_barrier(0); \
                          __builtin_amdgcn_s_setprio(1); } while (0)
#define PH_BAR_OUT() do { __builtin_amdgcn_s_setprio(0); \
                          __builtin_amdgcn_sched_barrier(0); \
                          __builtin_amdgcn_s_barrier(); } while (0)

  for (int u = 0; u < NT; ++u) {
    const uint16_t* Ab = &lds[(u & 3) * 16384 + rA];
    const uint16_t* Bb = &lds[(u & 3) * 16384 + 8192 + rB];
    const int us = (u + 3 < NT) ? (u + 3) : (NT - 1);  // clamp: uniform vmcnt
    uint16_t* sb = &lds[((u + 3) & 3) * 16384];
    const size_t kofs = (size_t)us * 32;

    asm volatile("s_waitcnt vmcnt(8)" ::: "memory");
    __builtin_amdgcn_s_barrier();

    bf16x8 af[8], bfr[4];
    // ---- ph0: A0-3, B0-1 ----
#pragma unroll
    for (int m = 0; m < 4; ++m) af[m] = *reinterpret_cast<const bf16x8*>(Ab + m * 512);
#pragma unroll
    for (int n = 0; n < 2; ++n) bfr[n] = *reinterpret_cast<const bf16x8*>(Bb + n * 512);
    gload_lds16(Ag0 + kofs, sb + sdw);
    PH_BAR_IN();
#pragma unroll
    for (int m = 0; m < 4; ++m)
#pragma unroll
      for (int n = 0; n < 2; ++n)
        acc[m][n] = __builtin_amdgcn_mfma_f32_16x16x32_bf16(bfr[n], af[m], acc[m][n], 0, 0, 0);
    PH_BAR_OUT();

    // ---- ph1: A4-7 ----
#pragma unroll
    for (int m = 4; m < 8; ++m) af[m] = *reinterpret_cast<const bf16x8*>(Ab + m * 512);
    gload_lds16(Ag1 + kofs, sb + 4096 + sdw);
    PH_BAR_IN();
#pragma unroll
    for (int m = 4; m < 8; ++m)
#pragma unroll
      for (int n = 0; n < 2; ++n)
        acc[m][n] = __builtin_amdgcn_mfma_f32_16x16x32_bf16(bfr[n], af[m], acc[m][n], 0, 0, 0);
    PH_BAR_OUT();

    // ---- ph2: B2-3 ----
#pragma unroll
    for (int n = 2; n < 4; ++n) bfr[n] = *reinterpret_cast<const bf16x8*>(Bb + n * 512);
    gload_lds16(Bg0 + kofs, sb + 8192 + sdw);
    PH_BAR_IN();
#pragma unroll
    for (int m = 0; m < 4; ++m)
#pragma unroll
      for (int n = 2; n < 4; ++n)
        acc[m][n] = __builtin_amdgcn_mfma_f32_16x16x32_bf16(bfr[n], af[m], acc[m][n], 0, 0, 0);
    PH_BAR_OUT();

    // ---- ph3 ----
    gload_lds16(Bg1 + kofs, sb + 12288 + sdw);
    PH_BAR_IN();
#pragma unroll
    for (int m = 4; m < 8; ++m)
#pragma unroll
      for (int n = 2; n < 4; ++n)
        acc[m][n] = __builtin_amdgcn_mfma_f32_16x16x32_bf16(bfr[n], af[m], acc[m][n], 0, 0, 0);
    __builtin_amdgcn_s_setprio(0);
    __builtin_amdgcn_sched_barrier(0);
    // next iter's fence barrier follows
  }
  asm volatile("s_waitcnt vmcnt(0)" ::: "memory");

  // ---- epilogue (operand-swapped layout):
  //   row = m0 + wr*128 + m*16 + (lane&15)
  //   col = n0 + wc*64 + n*16 + (lane>>4)*4 + i   -> 4 consecutive cols/lane
  const int r0 = m0 + wr * 128 + (lane & 15);
  const int cb = n0 + wc * 64 + (lane >> 4) * 4;
  if constexpr (OUT_BF16_BIAS) {
    uint16_t* C = (uint16_t*)Cout;
#pragma unroll
    for (int n = 0; n < 4; ++n) {
      const int col = cb + n * 16;
      const float4 bv = *reinterpret_cast<const float4*>(&bias[col]);
#pragma unroll
      for (int m = 0; m < 8; ++m) {
        const int row = r0 + m * 16;
        ushort4 o;
        o.x = f32_to_bf16(acc[m][n][0] + bv.x);
        o.y = f32_to_bf16(acc[m][n][1] + bv.y);
        o.z = f32_to_bf16(acc[m][n][2] + bv.z);
        o.w = f32_to_bf16(acc[m][n][3] + bv.w);
        *reinterpret_cast<ushort4*>(&C[(size_t)row * N + col]) = o;
      }
    }
  } else {
    float* C = (float*)Cout;
#pragma unroll
    for (int n = 0; n < 4; ++n) {
      const int col = cb + n * 16;
#pragma unroll
      for (int m = 0; m < 8; ++m) {
        const int row = r0 + m * 16;
        float4 o;
        o.x = acc[m][n][0]; o.y = acc[m][n][1];
        o.z = acc[m][n][2]; o.w = acc[m][n][3];
        *reinterpret_cast<float4*>(&C[(size_t)row * N + col]) = o;
      }
    }
  }
#undef PH_BAR_IN
#undef PH_BAR_OUT
}

// ---------------- scan: h_t = a_t*h_{t-1} + v_t,  h_0 = 0.5 ----------------
__device__ __forceinline__ void gate_val(float kz, float hx, float& a, float& v) {
  float ek = __expf(-fabsf(kz));
  float r  = 1.0f / (1.0f + ek);
  float z  = (kz >= 0.0f) ? r : ek * r;   // sigmoid(k)
  a        = (kz >= 0.0f) ? ek * r : r;   // 1 - sigmoid(k)
  float g;
  if (hx >= 0.0f) {
    g = hx + 0.5f;
  } else {
    float eh = __expf(hx);
    g = eh / (1.0f + eh);
  }
  v = z * g;
}

__global__ __launch_bounds__(256) void scan_pass1(
    const uint16_t* __restrict__ proj, float* __restrict__ Ac,
    float* __restrict__ Vc, int T, int E, int CH, int L) {
  const int e = blockIdx.x * 256 + threadIdx.x;
  const int c = blockIdx.y;
  const int b = blockIdx.z;
  const int N1 = 2 * E;
  const uint16_t* p = proj + (size_t)(b * T + c * L) * N1 + e;
  float A = 1.0f, V = 0.0f;
  for (int t = 0; t < L; ++t) {
    float kz = bf16_to_f32(p[0]);
    float hx = bf16_to_f32(p[E]);
    float a, v; gate_val(kz, hx, a, v);
    A *= a;
    V = a * V + v;
    p += N1;
  }
  const size_t idx = ((size_t)(b * CH + c)) * E + e;
  Ac[idx] = A; Vc[idx] = V;
}

__global__ __launch_bounds__(256) void scan_pass2(
    const float* __restrict__ Ac, const float* __restrict__ Vc,
    float* __restrict__ hstart, int E, int CH) {
  const int e = blockIdx.x * 256 + threadIdx.x;
  const int b = blockIdx.y;
  float h = 0.5f;
  for (int c = 0; c < CH; ++c) {
    const size_t idx = ((size_t)(b * CH + c)) * E + e;
    hstart[idx] = h;
    h = Ac[idx] * h + Vc[idx];
  }
}

__global__ __launch_bounds__(256) void scan_pass3(
    const uint16_t* __restrict__ proj, const float* __restrict__ hstart,
    uint16_t* __restrict__ hout, int T, int E, int CH, int L) {
  const int e = blockIdx.x * 256 + threadIdx.x;
  const int c = blockIdx.y;
  const int b = blockIdx.z;
  const int N1 = 2 * E;
  const uint16_t* p = proj + (size_t)(b * T + c * L) * N1 + e;
  uint16_t* o = hout + (size_t)(b * T + c * L) * E + e;
  float h = hstart[((size_t)(b * CH + c)) * E + e];
  for (int t = 0; t < L; ++t) {
    float kz = bf16_to_f32(p[0]);
    float hx = bf16_to_f32(p[E]);
    float a, v; gate_val(kz, hx, a, v);
    h = a * h + v;
    *o = f32_to_bf16(h);
    p += N1; o += E;
  }
}

extern "C" void kernel_launch(void* const* d_in, const int* in_sizes, int n_in,
                              void* d_out, int out_size, void* d_ws, size_t ws_size,
                              hipStream_t stream) {
  const float* x   = (const float*)d_in[0];
  const float* W_f = (const float*)d_in[1];
  const float* b_f = (const float*)d_in[2];
  const float* W_d = (const float*)d_in[3];
  const int Bb = 4, T = 4096, D = 1024, E = 1536;
  const int M = Bb * T;        // 16384
  const int N1 = 2 * E;        // 3072
  const int CH = 64, L = T / CH;

  char* w = (char*)d_ws;
  uint16_t* x_bf  = (uint16_t*)w; w += (size_t)M * D * 2;
  uint16_t* Wf_bf = (uint16_t*)w; w += (size_t)N1 * D * 2;
  uint16_t* Wd_bf = (uint16_t*)w; w += (size_t)D * E * 2;
  uint16_t* proj  = (uint16_t*)w; w += (size_t)M * N1 * 2;
  uint16_t* h_bf  = (uint16_t*)w; w += (size_t)M * E * 2;
  float* Ac     = (float*)w; w += (size_t)Bb * CH * E * 4;
  float* Vc     = (float*)w; w += (size_t)Bb * CH * E * 4;
  float* hstart = (float*)w; w += (size_t)Bb * CH * E * 4;

  cast_f32_bf16<<<M * D / 4 / 256, 256, 0, stream>>>(x, x_bf, M * D / 4);
  cast_f32_bf16<<<N1 * D / 4 / 256, 256, 0, stream>>>(W_f, Wf_bf, N1 * D / 4);
  cast_f32_bf16<<<D * E / 4 / 256, 256, 0, stream>>>(W_d, Wd_bf, D * E / 4);

  // proj = x @ W_f^T + b_f (bf16 out);  grid 768 (= 64 m-tiles x 12 n-tiles)
  gemm256<1><<<(M / 256) * (N1 / 256), 512, 0, stream>>>(
      x_bf, Wf_bf, b_f, proj, M, N1, D);

  scan_pass1<<<dim3(E / 256, CH, Bb), 256, 0, stream>>>(proj, Ac, Vc, T, E, CH, L);
  scan_pass2<<<dim3(E / 256, Bb), 256, 0, stream>>>(Ac, Vc, hstart, E, CH);
  scan_pass3<<<dim3(E / 256, CH, Bb), 256, 0, stream>>>(proj, hstart, h_bf, T, E, CH, L);

  // out = h @ W_down^T (fp32 out);  grid 256 (= 64 m-tiles x 4 n-tiles)
  gemm256<0><<<(M / 256) * (D / 256), 512, 0, stream>>>(
      h_bf, Wd_bf, nullptr, d_out, M, D, E);
}